// Round 4
// baseline (523.313 us; speedup 1.0000x reference)
//
#include <hip/hip_runtime.h>
#include <stdint.h>

// ---------------------------------------------------------------------------
// GAT layer, dtype-adaptive:
//   flags[0]: edge_index is int64 (1) or int32 (0)   -- probed at runtime
//   flags[1]: float tensors are bf16 (1) or fp32 (0) -- probed at runtime
// Pipeline: h = x@W (fp32 vector GEMM) -> a_src/a_dst -> CSR by dst ->
// per-node softmax+aggregate (no max-subtraction: |e| <~ 5; no output atomics).
// ---------------------------------------------------------------------------

__device__ __forceinline__ float b2f(unsigned short u) {
    union { unsigned int i; float f; } v; v.i = ((unsigned int)u) << 16; return v.f;
}
__device__ __forceinline__ unsigned short f2b(float f) {
    union { float f; unsigned int i; } v; v.f = f;
    unsigned int i = v.i;
    unsigned int r = (i + 0x7FFFu + ((i >> 16) & 1u)) >> 16;  // RNE
    return (unsigned short)r;
}

// --- 0. dtype probes --------------------------------------------------------
// flags[0]=1 iff odd 32-bit words of edge_index are all zero (int64 LE).
// flags[1]=1 iff low uint16 of x-words looks like bf16 (exponent plausible).
__global__ void k_detect(const int* __restrict__ eidx, const unsigned int* __restrict__ xw,
                         int* flags) {
    __shared__ int nz, bf;
    if (threadIdx.x == 0) { nz = 0; bf = 0; }
    __syncthreads();
    int bad = 0;
    for (int i = threadIdx.x; i < 1024; i += 256)
        if (eidx[2 * i + 1] != 0) bad = 1;
    if (bad) atomicOr(&nz, 1);
    int hits = 0;
    for (int i = threadIdx.x; i < 4096; i += 256) {
        unsigned int e = (xw[i] >> 7) & 0xFFu;   // exponent of low half as bf16
        if (e >= 0x60u && e < 0xA0u) ++hits;
    }
    atomicAdd(&bf, hits);
    __syncthreads();
    if (threadIdx.x == 0) {
        flags[0] = (nz == 0) ? 1 : 0;
        flags[1] = (bf > 3072) ? 1 : 0;
    }
}

__device__ __forceinline__ int edge_at(const int* idx32, const long long* idx64,
                                       int is64, long long pos) {
    return is64 ? (int)idx64[pos] : idx32[pos];
}

// --- 0b. convert W / att / bias to fp32 in ws -------------------------------
__global__ void k_prep(const void* __restrict__ Wv, const void* __restrict__ asv,
                       const void* __restrict__ adv, const void* __restrict__ bv,
                       const int* __restrict__ flags,
                       float* __restrict__ Wf, float* __restrict__ attf /*256*/,
                       float* __restrict__ biasf /*128*/) {
    int isbf = flags[1];
    int tid = blockIdx.x * 256 + threadIdx.x;
    for (int i = tid; i < 16384; i += gridDim.x * 256)
        Wf[i] = isbf ? b2f(((const unsigned short*)Wv)[i]) : ((const float*)Wv)[i];
    if (blockIdx.x == 0) {
        for (int i = threadIdx.x; i < 128; i += 256) {
            attf[i]       = isbf ? b2f(((const unsigned short*)asv)[i]) : ((const float*)asv)[i];
            attf[128 + i] = isbf ? b2f(((const unsigned short*)adv)[i]) : ((const float*)adv)[i];
            biasf[i]      = isbf ? b2f(((const unsigned short*)bv)[i]) : ((const float*)bv)[i];
        }
    }
}

// --- 1. h = x @ W, fp32 vector GEMM. Block: 256 thr, 64 rows x 128 cols. ---
__global__ __launch_bounds__(256) void k_gemm(const void* __restrict__ xv,
                                              const float* __restrict__ Wf,
                                              const int* __restrict__ flags,
                                              float* __restrict__ h, int N) {
    __shared__ float xs[64 * 128];
    int tid = threadIdx.x;
    int r0 = blockIdx.x * 64;
    int isbf = flags[1];
    if (isbf) {
        const unsigned short* xb = (const unsigned short*)xv;
#pragma unroll
        for (int it = 0; it < 8; ++it) {
            int e = it * 1024 + tid * 4;
            int r = e >> 7, k = e & 127;
            int gr = r0 + r; if (gr >= N) gr = N - 1;
            ushort4 v = *(const ushort4*)(xb + (size_t)gr * 128 + k);
            float4 f; f.x = b2f(v.x); f.y = b2f(v.y); f.z = b2f(v.z); f.w = b2f(v.w);
            *(float4*)(&xs[r * 128 + k]) = f;
        }
    } else {
        const float* xf = (const float*)xv;
#pragma unroll
        for (int it = 0; it < 8; ++it) {
            int e = it * 1024 + tid * 4;
            int r = e >> 7, k = e & 127;
            int gr = r0 + r; if (gr >= N) gr = N - 1;
            *(float4*)(&xs[r * 128 + k]) = *(const float4*)(xf + (size_t)gr * 128 + k);
        }
    }
    __syncthreads();

    int colg = (tid & 31) * 4;
    int rowg = (tid >> 5) * 8;
    float acc[8][4];
#pragma unroll
    for (int r = 0; r < 8; ++r)
#pragma unroll
        for (int j = 0; j < 4; ++j) acc[r][j] = 0.f;

#pragma unroll 4
    for (int k = 0; k < 128; ++k) {
        float4 w4 = *(const float4*)(Wf + k * 128 + colg);
#pragma unroll
        for (int r = 0; r < 8; ++r) {
            float xv_ = xs[(rowg + r) * 128 + k];
            acc[r][0] += xv_ * w4.x;
            acc[r][1] += xv_ * w4.y;
            acc[r][2] += xv_ * w4.z;
            acc[r][3] += xv_ * w4.w;
        }
    }
#pragma unroll
    for (int r = 0; r < 8; ++r) {
        int gr = r0 + rowg + r;
        if (gr < N) {
            float4 v; v.x = acc[r][0]; v.y = acc[r][1]; v.z = acc[r][2]; v.w = acc[r][3];
            *(float4*)(&h[(size_t)gr * 128 + colg]) = v;
        }
    }
}

// --- 2. a_src[n,h], a_dst[n,h] ---------------------------------------------
__global__ void k_attn(const float* __restrict__ h,
                       const float* __restrict__ attf,
                       float* __restrict__ asf, float* __restrict__ adf, int N4) {
    int t = blockIdx.x * 256 + threadIdx.x;
    if (t >= N4) return;
    int n = t >> 2, hd = t & 3;
    const float* hp = h + (size_t)n * 128 + hd * 32;
    float s1 = 0.f, s2 = 0.f;
#pragma unroll
    for (int c = 0; c < 32; c += 4) {
        float4 hv = *(const float4*)(hp + c);
        float4 a1 = *(const float4*)(attf + hd * 32 + c);
        float4 a2 = *(const float4*)(attf + 128 + hd * 32 + c);
        s1 += hv.x * a1.x + hv.y * a1.y + hv.z * a1.z + hv.w * a1.w;
        s2 += hv.x * a2.x + hv.y * a2.y + hv.z * a2.z + hv.w * a2.w;
    }
    asf[t] = s1; adf[t] = s2;
}

// --- 3. CSR build by destination -------------------------------------------
__global__ void k_initcnt(int* cnt, int N) {
    int n = blockIdx.x * 256 + threadIdx.x;
    if (n < N) cnt[n] = 1;                    // self-loop
}
__global__ void k_count(const int* __restrict__ idx32, const long long* __restrict__ idx64,
                        const int* __restrict__ flags, int* cnt, int E) {
    int e = blockIdx.x * 256 + threadIdx.x;
    int is64 = flags[0];
    if (e < E) atomicAdd(&cnt[edge_at(idx32, idx64, is64, (long long)E + e)], 1);
}
__global__ void k_scan1(const int* __restrict__ cnt, int* bsum, int N) {
    __shared__ int sh[256];
    int tid = threadIdx.x;
    int i0 = blockIdx.x * 1024 + tid * 4;
    int s = 0;
#pragma unroll
    for (int j = 0; j < 4; ++j) { int i = i0 + j; if (i < N) s += cnt[i]; }
    sh[tid] = s; __syncthreads();
    for (int st = 128; st > 0; st >>= 1) {
        if (tid < st) sh[tid] += sh[tid + st];
        __syncthreads();
    }
    if (tid == 0) bsum[blockIdx.x] = sh[0];
}
__global__ void k_scan2(const int* __restrict__ bsum, int* boff, int* off, int numB, int N) {
    __shared__ int sh[256];
    int tid = threadIdx.x;
    int v = (tid < numB) ? bsum[tid] : 0;
    sh[tid] = v; __syncthreads();
    for (int st = 1; st < 256; st <<= 1) {
        int t = (tid >= st) ? sh[tid - st] : 0;
        __syncthreads();
        sh[tid] += t;
        __syncthreads();
    }
    boff[tid] = sh[tid] - v;                  // exclusive
    if (tid == 255) off[N] = sh[255];
}
__global__ void k_scan3(const int* __restrict__ cnt, const int* __restrict__ boff,
                        int* off, int N) {
    __shared__ int sh[256];
    int tid = threadIdx.x;
    int i0 = blockIdx.x * 1024 + tid * 4;
    int s = 0;
#pragma unroll
    for (int j = 0; j < 4; ++j) { int i = i0 + j; if (i < N) s += cnt[i]; }
    sh[tid] = s; __syncthreads();
    for (int st = 1; st < 256; st <<= 1) {
        int t = (tid >= st) ? sh[tid - st] : 0;
        __syncthreads();
        sh[tid] += t;
        __syncthreads();
    }
    int run = boff[blockIdx.x] + sh[tid] - s; // exclusive prefix
#pragma unroll
    for (int j = 0; j < 4; ++j) {
        int i = i0 + j;
        if (i < N) { off[i] = run; run += cnt[i]; }
    }
}
__global__ void k_selfloop(const int* __restrict__ off, int* cursor, int* esrc, int N) {
    int n = blockIdx.x * 256 + threadIdx.x;
    if (n < N) { int o = off[n]; esrc[o] = n; cursor[n] = o + 1; }
}
__global__ void k_scatter(const int* __restrict__ idx32, const long long* __restrict__ idx64,
                          const int* __restrict__ flags, int* cursor, int* esrc, int E) {
    int e = blockIdx.x * 256 + threadIdx.x;
    int is64 = flags[0];
    if (e < E) {
        int s = edge_at(idx32, idx64, is64, e);
        int d = edge_at(idx32, idx64, is64, (long long)E + e);
        int pos = atomicAdd(&cursor[d], 1);
        esrc[pos] = s;
    }
}

// --- 4. per-node softmax + aggregate. Block = node, 128 thr = 1 channel ----
#define MAXD 512
__global__ __launch_bounds__(128) void k_aggregate(
    const float* __restrict__ h,
    const float* __restrict__ asf, const float* __restrict__ adf,
    const int* __restrict__ off, const int* __restrict__ cnt,
    const int* __restrict__ esrc,
    const float* __restrict__ biasf,
    const int* __restrict__ flags,
    void* __restrict__ outv, int N) {
    int n = blockIdx.x;
    int tid = threadIdx.x;
    int head = tid >> 5;
    __shared__ int src_sh[MAXD];
    __shared__ float p_sh[MAXD * 4];
    __shared__ float red[4 * 128];

    int start = off[n];
    int deg = cnt[n];
    float ad0 = adf[n * 4 + 0], ad1 = adf[n * 4 + 1];
    float ad2 = adf[n * 4 + 2], ad3 = adf[n * 4 + 3];
    bool cached = (deg <= MAXD);

    float ps0 = 0.f, ps1 = 0.f, ps2 = 0.f, ps3 = 0.f;
    for (int i = tid; i < deg; i += 128) {
        int s = esrc[start + i];
        float e0 = asf[s * 4 + 0] + ad0; e0 = fmaxf(e0, 0.2f * e0); float p0 = __expf(e0);
        float e1 = asf[s * 4 + 1] + ad1; e1 = fmaxf(e1, 0.2f * e1); float p1 = __expf(e1);
        float e2 = asf[s * 4 + 2] + ad2; e2 = fmaxf(e2, 0.2f * e2); float p2 = __expf(e2);
        float e3 = asf[s * 4 + 3] + ad3; e3 = fmaxf(e3, 0.2f * e3); float p3 = __expf(e3);
        ps0 += p0; ps1 += p1; ps2 += p2; ps3 += p3;
        if (cached) {
            src_sh[i] = s;
            p_sh[i * 4 + 0] = p0; p_sh[i * 4 + 1] = p1;
            p_sh[i * 4 + 2] = p2; p_sh[i * 4 + 3] = p3;
        }
    }
    red[tid] = ps0; red[128 + tid] = ps1; red[256 + tid] = ps2; red[384 + tid] = ps3;
    __syncthreads();
    for (int s2 = 64; s2 > 0; s2 >>= 1) {
        if (tid < s2) {
            red[tid] += red[tid + s2];
            red[128 + tid] += red[128 + tid + s2];
            red[256 + tid] += red[256 + tid + s2];
            red[384 + tid] += red[384 + tid + s2];
        }
        __syncthreads();
    }
    float adh  = head == 0 ? ad0 : head == 1 ? ad1 : head == 2 ? ad2 : ad3;
    float invh = 1.0f / (red[head * 128] + 1e-16f);

    float acc = 0.f;
    if (cached) {
        int i = 0;
        for (; i + 1 < deg; i += 2) {
            int s0 = src_sh[i], s1 = src_sh[i + 1];
            float hv0 = h[(size_t)s0 * 128 + tid];
            float hv1 = h[(size_t)s1 * 128 + tid];
            acc += p_sh[i * 4 + head] * hv0;
            acc += p_sh[(i + 1) * 4 + head] * hv1;
        }
        if (i < deg) {
            int s0 = src_sh[i];
            acc += p_sh[i * 4 + head] * h[(size_t)s0 * 128 + tid];
        }
    } else {
        for (int i = 0; i < deg; ++i) {
            int s = esrc[start + i];
            float e = asf[s * 4 + head] + adh; e = fmaxf(e, 0.2f * e);
            acc += __expf(e) * h[(size_t)s * 128 + tid];
        }
    }
    acc = acc * invh + biasf[tid];
    if (flags[1]) ((unsigned short*)outv)[(size_t)n * 128 + tid] = f2b(acc);
    else          ((float*)outv)[(size_t)n * 128 + tid] = acc;
}

// ---------------------------------------------------------------------------
extern "C" void kernel_launch(void* const* d_in, const int* in_sizes, int n_in,
                              void* d_out, int out_size, void* d_ws, size_t ws_size,
                              hipStream_t stream) {
    const void*      xv    = d_in[0];
    const int*       idx32 = (const int*)d_in[1];
    const long long* idx64 = (const long long*)d_in[1];

    int N = in_sizes[0] / 128;
    int E = in_sizes[1] / 2;

    char* ws = (char*)d_ws;
    size_t o = 0;
    auto alloc = [&](size_t bytes) {
        size_t r = o; o += (bytes + 255) & ~(size_t)255; return r;
    };
    float* h     = (float*)(ws + alloc((size_t)N * 128 * 4));
    float* Wf    = (float*)(ws + alloc(16384 * 4));
    float* attf  = (float*)(ws + alloc(256 * 4));
    float* biasf = (float*)(ws + alloc(128 * 4));
    float* asf   = (float*)(ws + alloc((size_t)N * 4 * 4));
    float* adf   = (float*)(ws + alloc((size_t)N * 4 * 4));
    int* cnt     = (int*)(ws + alloc((size_t)N * 4));
    int* offs    = (int*)(ws + alloc((size_t)(N + 1) * 4));
    int* cursor  = (int*)(ws + alloc((size_t)N * 4));
    int* bsum    = (int*)(ws + alloc(256 * 4));
    int* boff    = (int*)(ws + alloc(256 * 4));
    int* flags   = (int*)(ws + alloc(256));
    int* esrc    = (int*)(ws + alloc((size_t)(E + N) * 4));

    int numB = (N + 1023) / 1024;

    k_detect<<<1, 256, 0, stream>>>(idx32, (const unsigned int*)xv, flags);
    k_prep<<<16, 256, 0, stream>>>(d_in[2], d_in[3], d_in[4], d_in[5], flags, Wf, attf, biasf);
    k_gemm<<<(N + 63) / 64, 256, 0, stream>>>(xv, Wf, flags, h, N);
    k_attn<<<(N * 4 + 255) / 256, 256, 0, stream>>>(h, attf, asf, adf, N * 4);
    k_initcnt<<<(N + 255) / 256, 256, 0, stream>>>(cnt, N);
    k_count<<<(E + 255) / 256, 256, 0, stream>>>(idx32, idx64, flags, cnt, E);
    k_scan1<<<numB, 256, 0, stream>>>(cnt, bsum, N);
    k_scan2<<<1, 256, 0, stream>>>(bsum, boff, offs, numB, N);
    k_scan3<<<numB, 256, 0, stream>>>(cnt, boff, offs, N);
    k_selfloop<<<(N + 255) / 256, 256, 0, stream>>>(offs, cursor, esrc, N);
    k_scatter<<<(E + 255) / 256, 256, 0, stream>>>(idx32, idx64, flags, cursor, esrc, E);
    k_aggregate<<<N, 128, 0, stream>>>(h, asf, adf, offs, cnt, esrc, biasf, flags, d_out, N);
}

// Round 6
// 464.131 us; speedup vs baseline: 1.1275x; 1.1275x over previous
//
#include <hip/hip_runtime.h>
#include <stdint.h>

// ---------------------------------------------------------------------------
// GAT layer, dtype-adaptive (probed: fp32 inputs, int32 edge_index, bf16 out).
//   h = x@W      fp32 vector GEMM, attn dots fused in epilogue, h stored bf16
//   CSR by dst   (count/scan/scatter)
//   aggregate    per-node softmax (no max-sub: |e|<~5) + gather of bf16 h rows
// ---------------------------------------------------------------------------

__device__ __forceinline__ float b2f(unsigned short u) {
    union { unsigned int i; float f; } v; v.i = ((unsigned int)u) << 16; return v.f;
}
__device__ __forceinline__ unsigned short f2b(float f) {
    union { float f; unsigned int i; } v; v.f = f;
    unsigned int i = v.i;
    unsigned int r = (i + 0x7FFFu + ((i >> 16) & 1u)) >> 16;  // RNE
    return (unsigned short)r;
}

// --- 0. dtype probes --------------------------------------------------------
__global__ void k_detect(const int* __restrict__ eidx, const unsigned int* __restrict__ xw,
                         int* flags) {
    __shared__ int nz, bf;
    if (threadIdx.x == 0) { nz = 0; bf = 0; }
    __syncthreads();
    int bad = 0;
    for (int i = threadIdx.x; i < 1024; i += 256)
        if (eidx[2 * i + 1] != 0) bad = 1;
    if (bad) atomicOr(&nz, 1);
    int hits = 0;
    for (int i = threadIdx.x; i < 4096; i += 256) {
        unsigned int e = (xw[i] >> 7) & 0xFFu;   // exponent of low half as bf16
        if (e >= 0x60u && e < 0xA0u) ++hits;
    }
    atomicAdd(&bf, hits);
    __syncthreads();
    if (threadIdx.x == 0) {
        flags[0] = (nz == 0) ? 1 : 0;   // 1 => int64 edge_index
        flags[1] = (bf > 3072) ? 1 : 0; // 1 => bf16 float tensors
    }
}

__device__ __forceinline__ int edge_at(const int* idx32, const long long* idx64,
                                       int is64, long long pos) {
    return is64 ? (int)idx64[pos] : idx32[pos];
}

// --- 0b. W / att / bias -> fp32 in ws ---------------------------------------
__global__ void k_prep(const void* __restrict__ Wv, const void* __restrict__ asv,
                       const void* __restrict__ adv, const void* __restrict__ bv,
                       const int* __restrict__ flags,
                       float* __restrict__ Wf, float* __restrict__ attf /*256*/,
                       float* __restrict__ biasf /*128*/) {
    int isbf = flags[1];
    int tid = blockIdx.x * 256 + threadIdx.x;
    for (int i = tid; i < 16384; i += gridDim.x * 256)
        Wf[i] = isbf ? b2f(((const unsigned short*)Wv)[i]) : ((const float*)Wv)[i];
    if (blockIdx.x == 0) {
        for (int i = threadIdx.x; i < 128; i += 256) {
            attf[i]       = isbf ? b2f(((const unsigned short*)asv)[i]) : ((const float*)asv)[i];
            attf[128 + i] = isbf ? b2f(((const unsigned short*)adv)[i]) : ((const float*)adv)[i];
            biasf[i]      = isbf ? b2f(((const unsigned short*)bv)[i]) : ((const float*)bv)[i];
        }
    }
}

// --- 1. h = x @ W (fp32), fused attn dots, h stored bf16. -------------------
//  Block: 256 thr; tile 64 rows x 128 cols. Thread: rows rowg..+7, cols colg..+3.
//  xs LDS reads are float4 broadcast (2 addrs/wave, conflict-free).
__global__ __launch_bounds__(256) void k_gemm(const void* __restrict__ xv,
                                              const float* __restrict__ Wf,
                                              const float* __restrict__ attf,
                                              const int* __restrict__ flags,
                                              unsigned short* __restrict__ hbf,
                                              float* __restrict__ asf,
                                              float* __restrict__ adf, int N) {
    __shared__ float xs[64 * 128];
    int tid = threadIdx.x;
    int r0 = blockIdx.x * 64;
    int isbf = flags[1];
    if (isbf) {
        const unsigned short* xb = (const unsigned short*)xv;
#pragma unroll
        for (int it = 0; it < 8; ++it) {
            int e = it * 1024 + tid * 4;
            int r = e >> 7, k = e & 127;
            int gr = r0 + r; if (gr >= N) gr = N - 1;
            ushort4 v = *(const ushort4*)(xb + (size_t)gr * 128 + k);
            float4 f; f.x = b2f(v.x); f.y = b2f(v.y); f.z = b2f(v.z); f.w = b2f(v.w);
            *(float4*)(&xs[r * 128 + k]) = f;
        }
    } else {
        const float* xf = (const float*)xv;
#pragma unroll
        for (int it = 0; it < 8; ++it) {
            int e = it * 1024 + tid * 4;
            int r = e >> 7, k = e & 127;
            int gr = r0 + r; if (gr >= N) gr = N - 1;
            *(float4*)(&xs[r * 128 + k]) = *(const float4*)(xf + (size_t)gr * 128 + k);
        }
    }
    __syncthreads();

    int colg = (tid & 31) * 4;
    int rowg = (tid >> 5) * 8;
    float as4[4], ad4[4];
#pragma unroll
    for (int j = 0; j < 4; ++j) {
        as4[j] = attf[colg + j];
        ad4[j] = attf[128 + colg + j];
    }
    float acc[8][4];
#pragma unroll
    for (int r = 0; r < 8; ++r)
#pragma unroll
        for (int j = 0; j < 4; ++j) acc[r][j] = 0.f;

#pragma unroll 2
    for (int k0 = 0; k0 < 128; k0 += 4) {
        float4 w0 = *(const float4*)(Wf + (k0 + 0) * 128 + colg);
        float4 w1 = *(const float4*)(Wf + (k0 + 1) * 128 + colg);
        float4 w2 = *(const float4*)(Wf + (k0 + 2) * 128 + colg);
        float4 w3 = *(const float4*)(Wf + (k0 + 3) * 128 + colg);
#pragma unroll
        for (int r = 0; r < 8; ++r) {
            float4 x4 = *(const float4*)(&xs[(rowg + r) * 128 + k0]);
            acc[r][0] += x4.x * w0.x + x4.y * w1.x + x4.z * w2.x + x4.w * w3.x;
            acc[r][1] += x4.x * w0.y + x4.y * w1.y + x4.z * w2.y + x4.w * w3.y;
            acc[r][2] += x4.x * w0.z + x4.y * w1.z + x4.z * w2.z + x4.w * w3.z;
            acc[r][3] += x4.x * w0.w + x4.y * w1.w + x4.z * w2.w + x4.w * w3.w;
        }
    }

    int hd = colg >> 5;                        // this thread's head (cols within one head)
#pragma unroll
    for (int r = 0; r < 8; ++r) {
        int gr = r0 + rowg + r;
        // per-head attn partials over this thread's 4 cols, reduce across the
        // 8 lanes (tid&7) that cover the head's 32 channels.
        float s1 = acc[r][0] * as4[0] + acc[r][1] * as4[1] + acc[r][2] * as4[2] + acc[r][3] * as4[3];
        float s2 = acc[r][0] * ad4[0] + acc[r][1] * ad4[1] + acc[r][2] * ad4[2] + acc[r][3] * ad4[3];
#pragma unroll
        for (int m = 1; m < 8; m <<= 1) {
            s1 += __shfl_xor(s1, m);
            s2 += __shfl_xor(s2, m);
        }
        if ((tid & 7) == 0 && gr < N) {
            asf[(size_t)gr * 4 + hd] = s1;
            adf[(size_t)gr * 4 + hd] = s2;
        }
        if (gr < N) {
            ushort4 hv;
            hv.x = f2b(acc[r][0]); hv.y = f2b(acc[r][1]);
            hv.z = f2b(acc[r][2]); hv.w = f2b(acc[r][3]);
            *(ushort4*)(&hbf[(size_t)gr * 128 + colg]) = hv;
        }
    }
}

// --- 2. CSR build by destination -------------------------------------------
__global__ void k_initcnt(int* cnt, int N) {
    int n = blockIdx.x * 256 + threadIdx.x;
    if (n < N) cnt[n] = 1;                    // self-loop
}
__global__ void k_count(const int* __restrict__ idx32, const long long* __restrict__ idx64,
                        const int* __restrict__ flags, int* cnt, int E) {
    int e = blockIdx.x * 256 + threadIdx.x;
    int is64 = flags[0];
    if (e < E) atomicAdd(&cnt[edge_at(idx32, idx64, is64, (long long)E + e)], 1);
}
__global__ void k_scan1(const int* __restrict__ cnt, int* bsum, int N) {
    __shared__ int sh[256];
    int tid = threadIdx.x;
    int i0 = blockIdx.x * 1024 + tid * 4;
    int s = 0;
#pragma unroll
    for (int j = 0; j < 4; ++j) { int i = i0 + j; if (i < N) s += cnt[i]; }
    sh[tid] = s; __syncthreads();
    for (int st = 128; st > 0; st >>= 1) {
        if (tid < st) sh[tid] += sh[tid + st];
        __syncthreads();
    }
    if (tid == 0) bsum[blockIdx.x] = sh[0];
}
__global__ void k_scan2(const int* __restrict__ bsum, int* boff, int* off, int numB, int N) {
    __shared__ int sh[256];
    int tid = threadIdx.x;
    int v = (tid < numB) ? bsum[tid] : 0;
    sh[tid] = v; __syncthreads();
    for (int st = 1; st < 256; st <<= 1) {
        int t = (tid >= st) ? sh[tid - st] : 0;
        __syncthreads();
        sh[tid] += t;
        __syncthreads();
    }
    boff[tid] = sh[tid] - v;                  // exclusive
    if (tid == 255) off[N] = sh[255];
}
__global__ void k_scan3(const int* __restrict__ cnt, const int* __restrict__ boff,
                        int* off, int N) {
    __shared__ int sh[256];
    int tid = threadIdx.x;
    int i0 = blockIdx.x * 1024 + tid * 4;
    int s = 0;
#pragma unroll
    for (int j = 0; j < 4; ++j) { int i = i0 + j; if (i < N) s += cnt[i]; }
    sh[tid] = s; __syncthreads();
    for (int st = 1; st < 256; st <<= 1) {
        int t = (tid >= st) ? sh[tid - st] : 0;
        __syncthreads();
        sh[tid] += t;
        __syncthreads();
    }
    int run = boff[blockIdx.x] + sh[tid] - s; // exclusive prefix
#pragma unroll
    for (int j = 0; j < 4; ++j) {
        int i = i0 + j;
        if (i < N) { off[i] = run; run += cnt[i]; }
    }
}
__global__ void k_selfloop(const int* __restrict__ off, int* cursor, int* esrc, int N) {
    int n = blockIdx.x * 256 + threadIdx.x;
    if (n < N) { int o = off[n]; esrc[o] = n; cursor[n] = o + 1; }
}
__global__ void k_scatter(const int* __restrict__ idx32, const long long* __restrict__ idx64,
                          const int* __restrict__ flags, int* cursor, int* esrc, int E) {
    int e = blockIdx.x * 256 + threadIdx.x;
    int is64 = flags[0];
    if (e < E) {
        int s = edge_at(idx32, idx64, is64, e);
        int d = edge_at(idx32, idx64, is64, (long long)E + e);
        int pos = atomicAdd(&cursor[d], 1);
        esrc[pos] = s;
    }
}

// --- 3. per-node softmax + aggregate (bf16 h gather, unroll 4) -------------
#define MAXD 256
__global__ __launch_bounds__(128) void k_aggregate(
    const unsigned short* __restrict__ hbf,
    const float* __restrict__ asf, const float* __restrict__ adf,
    const int* __restrict__ off, const int* __restrict__ cnt,
    const int* __restrict__ esrc,
    const float* __restrict__ biasf,
    const int* __restrict__ flags,
    void* __restrict__ outv, int N) {
    int n = blockIdx.x;
    int tid = threadIdx.x;
    int head = tid >> 5;
    __shared__ int src_sh[MAXD];
    __shared__ float p_sh[MAXD * 4];
    __shared__ float red[4 * 128];

    int start = off[n];
    int deg = cnt[n];
    float ad0 = adf[n * 4 + 0], ad1 = adf[n * 4 + 1];
    float ad2 = adf[n * 4 + 2], ad3 = adf[n * 4 + 3];
    bool cached = (deg <= MAXD);

    float ps0 = 0.f, ps1 = 0.f, ps2 = 0.f, ps3 = 0.f;
    for (int i = tid; i < deg; i += 128) {
        int s = esrc[start + i];
        float4 av = *(const float4*)(asf + (size_t)s * 4);
        float e0 = av.x + ad0; e0 = fmaxf(e0, 0.2f * e0); float p0 = __expf(e0);
        float e1 = av.y + ad1; e1 = fmaxf(e1, 0.2f * e1); float p1 = __expf(e1);
        float e2 = av.z + ad2; e2 = fmaxf(e2, 0.2f * e2); float p2 = __expf(e2);
        float e3 = av.w + ad3; e3 = fmaxf(e3, 0.2f * e3); float p3 = __expf(e3);
        ps0 += p0; ps1 += p1; ps2 += p2; ps3 += p3;
        if (cached) {
            src_sh[i] = s;
            p_sh[i * 4 + 0] = p0; p_sh[i * 4 + 1] = p1;
            p_sh[i * 4 + 2] = p2; p_sh[i * 4 + 3] = p3;
        }
    }
    red[tid] = ps0; red[128 + tid] = ps1; red[256 + tid] = ps2; red[384 + tid] = ps3;
    __syncthreads();
    for (int s2 = 64; s2 > 0; s2 >>= 1) {
        if (tid < s2) {
            red[tid] += red[tid + s2];
            red[128 + tid] += red[128 + tid + s2];
            red[256 + tid] += red[256 + tid + s2];
            red[384 + tid] += red[384 + tid + s2];
        }
        __syncthreads();
    }
    float adh  = head == 0 ? ad0 : head == 1 ? ad1 : head == 2 ? ad2 : ad3;
    float invh = 1.0f / (red[head * 128] + 1e-16f);

    float acc = 0.f;
    if (cached) {
        int i = 0;
        for (; i + 3 < deg; i += 4) {          // 4 gathers in flight
            int s0 = src_sh[i], s1 = src_sh[i + 1], s2 = src_sh[i + 2], s3 = src_sh[i + 3];
            float h0 = b2f(hbf[(size_t)s0 * 128 + tid]);
            float h1 = b2f(hbf[(size_t)s1 * 128 + tid]);
            float h2 = b2f(hbf[(size_t)s2 * 128 + tid]);
            float h3 = b2f(hbf[(size_t)s3 * 128 + tid]);
            acc += p_sh[i * 4 + head] * h0 + p_sh[(i + 1) * 4 + head] * h1
                 + p_sh[(i + 2) * 4 + head] * h2 + p_sh[(i + 3) * 4 + head] * h3;
        }
        for (; i < deg; ++i) {
            int s0 = src_sh[i];
            acc += p_sh[i * 4 + head] * b2f(hbf[(size_t)s0 * 128 + tid]);
        }
    } else {                                   // pathological degree fallback
        for (int i = 0; i < deg; ++i) {
            int s = esrc[start + i];
            float e = asf[(size_t)s * 4 + head] + adh; e = fmaxf(e, 0.2f * e);
            acc += __expf(e) * b2f(hbf[(size_t)s * 128 + tid]);
        }
    }
    acc = acc * invh + biasf[tid];
    if (flags[1]) ((unsigned short*)outv)[(size_t)n * 128 + tid] = f2b(acc);
    else          ((float*)outv)[(size_t)n * 128 + tid] = acc;
}

// ---------------------------------------------------------------------------
extern "C" void kernel_launch(void* const* d_in, const int* in_sizes, int n_in,
                              void* d_out, int out_size, void* d_ws, size_t ws_size,
                              hipStream_t stream) {
    const void*      xv    = d_in[0];
    const int*       idx32 = (const int*)d_in[1];
    const long long* idx64 = (const long long*)d_in[1];

    int N = in_sizes[0] / 128;
    int E = in_sizes[1] / 2;

    char* ws = (char*)d_ws;
    size_t o = 0;
    auto alloc = [&](size_t bytes) {
        size_t r = o; o += (bytes + 255) & ~(size_t)255; return r;
    };
    unsigned short* hbf = (unsigned short*)(ws + alloc((size_t)N * 128 * 2));
    float* Wf    = (float*)(ws + alloc(16384 * 4));
    float* attf  = (float*)(ws + alloc(256 * 4));
    float* biasf = (float*)(ws + alloc(128 * 4));
    float* asf   = (float*)(ws + alloc((size_t)N * 4 * 4));
    float* adf   = (float*)(ws + alloc((size_t)N * 4 * 4));
    int* cnt     = (int*)(ws + alloc((size_t)N * 4));
    int* offs    = (int*)(ws + alloc((size_t)(N + 1) * 4));
    int* cursor  = (int*)(ws + alloc((size_t)N * 4));
    int* bsum    = (int*)(ws + alloc(256 * 4));
    int* boff    = (int*)(ws + alloc(256 * 4));
    int* flags   = (int*)(ws + alloc(256));
    int* esrc    = (int*)(ws + alloc((size_t)(E + N) * 4));

    int numB = (N + 1023) / 1024;

    k_detect<<<1, 256, 0, stream>>>(idx32, (const unsigned int*)xv, flags);
    k_prep<<<16, 256, 0, stream>>>(d_in[2], d_in[3], d_in[4], d_in[5], flags, Wf, attf, biasf);
    k_gemm<<<(N + 63) / 64, 256, 0, stream>>>(xv, Wf, attf, flags, hbf, asf, adf, N);
    k_initcnt<<<(N + 255) / 256, 256, 0, stream>>>(cnt, N);
    k_count<<<(E + 255) / 256, 256, 0, stream>>>(idx32, idx64, flags, cnt, E);
    k_scan1<<<numB, 256, 0, stream>>>(cnt, bsum, N);
    k_scan2<<<1, 256, 0, stream>>>(bsum, boff, offs, numB, N);
    k_scan3<<<numB, 256, 0, stream>>>(cnt, boff, offs, N);
    k_selfloop<<<(N + 255) / 256, 256, 0, stream>>>(offs, cursor, esrc, N);
    k_scatter<<<(E + 255) / 256, 256, 0, stream>>>(idx32, idx64, flags, cursor, esrc, E);
    k_aggregate<<<N, 128, 0, stream>>>(hbf, asf, adf, offs, cnt, esrc, biasf, flags, d_out, N);
}

// Round 7
// 378.928 us; speedup vs baseline: 1.3810x; 1.2249x over previous
//
#include <hip/hip_runtime.h>
#include <stdint.h>

// ---------------------------------------------------------------------------
// GAT layer, dtype-adaptive (probed: fp32 inputs, int32 edge_index, bf16 out).
//   h = x@W      fp32 vector GEMM, attn dots fused in epilogue, h stored bf16
//   slotted CSR  esrc[n*64+slot], slot via one atomicAdd pass (self-loop slot0)
//   aggregate    one WAVE per node: phase1 one-edge-per-lane softmax numerators,
//                butterfly denominators, phase2 dword gathers (2 ch/lane)
// ---------------------------------------------------------------------------

#define SLOT 64

__device__ __forceinline__ float b2f(unsigned short u) {
    union { unsigned int i; float f; } v; v.i = ((unsigned int)u) << 16; return v.f;
}
__device__ __forceinline__ unsigned short f2b(float f) {
    union { float f; unsigned int i; } v; v.f = f;
    unsigned int i = v.i;
    unsigned int r = (i + 0x7FFFu + ((i >> 16) & 1u)) >> 16;  // RNE
    return (unsigned short)r;
}

// --- 0. dtype probes --------------------------------------------------------
__global__ void k_detect(const int* __restrict__ eidx, const unsigned int* __restrict__ xw,
                         int* flags) {
    __shared__ int nz, bf;
    if (threadIdx.x == 0) { nz = 0; bf = 0; }
    __syncthreads();
    int bad = 0;
    for (int i = threadIdx.x; i < 1024; i += 256)
        if (eidx[2 * i + 1] != 0) bad = 1;
    if (bad) atomicOr(&nz, 1);
    int hits = 0;
    for (int i = threadIdx.x; i < 4096; i += 256) {
        unsigned int e = (xw[i] >> 7) & 0xFFu;   // exponent of low half as bf16
        if (e >= 0x60u && e < 0xA0u) ++hits;
    }
    atomicAdd(&bf, hits);
    __syncthreads();
    if (threadIdx.x == 0) {
        flags[0] = (nz == 0) ? 1 : 0;   // 1 => int64 edge_index
        flags[1] = (bf > 3072) ? 1 : 0; // 1 => bf16 float tensors
    }
}

__device__ __forceinline__ int edge_at(const int* idx32, const long long* idx64,
                                       int is64, long long pos) {
    return is64 ? (int)idx64[pos] : idx32[pos];
}

// --- 0b. W / att / bias -> fp32 in ws ---------------------------------------
__global__ void k_prep(const void* __restrict__ Wv, const void* __restrict__ asv,
                       const void* __restrict__ adv, const void* __restrict__ bv,
                       const int* __restrict__ flags,
                       float* __restrict__ Wf, float* __restrict__ attf /*256*/,
                       float* __restrict__ biasf /*128*/) {
    int isbf = flags[1];
    int tid = blockIdx.x * 256 + threadIdx.x;
    for (int i = tid; i < 16384; i += gridDim.x * 256)
        Wf[i] = isbf ? b2f(((const unsigned short*)Wv)[i]) : ((const float*)Wv)[i];
    if (blockIdx.x == 0) {
        for (int i = threadIdx.x; i < 128; i += 256) {
            attf[i]       = isbf ? b2f(((const unsigned short*)asv)[i]) : ((const float*)asv)[i];
            attf[128 + i] = isbf ? b2f(((const unsigned short*)adv)[i]) : ((const float*)adv)[i];
            biasf[i]      = isbf ? b2f(((const unsigned short*)bv)[i]) : ((const float*)bv)[i];
        }
    }
}

// --- 1. h = x @ W (fp32), fused attn dots, h stored bf16. -------------------
__global__ __launch_bounds__(256) void k_gemm(const void* __restrict__ xv,
                                              const float* __restrict__ Wf,
                                              const float* __restrict__ attf,
                                              const int* __restrict__ flags,
                                              unsigned short* __restrict__ hbf,
                                              float* __restrict__ asf,
                                              float* __restrict__ adf, int N) {
    __shared__ float xs[64 * 128];
    int tid = threadIdx.x;
    int r0 = blockIdx.x * 64;
    int isbf = flags[1];
    if (isbf) {
        const unsigned short* xb = (const unsigned short*)xv;
#pragma unroll
        for (int it = 0; it < 8; ++it) {
            int e = it * 1024 + tid * 4;
            int r = e >> 7, k = e & 127;
            int gr = r0 + r; if (gr >= N) gr = N - 1;
            ushort4 v = *(const ushort4*)(xb + (size_t)gr * 128 + k);
            float4 f; f.x = b2f(v.x); f.y = b2f(v.y); f.z = b2f(v.z); f.w = b2f(v.w);
            *(float4*)(&xs[r * 128 + k]) = f;
        }
    } else {
        const float* xf = (const float*)xv;
#pragma unroll
        for (int it = 0; it < 8; ++it) {
            int e = it * 1024 + tid * 4;
            int r = e >> 7, k = e & 127;
            int gr = r0 + r; if (gr >= N) gr = N - 1;
            *(float4*)(&xs[r * 128 + k]) = *(const float4*)(xf + (size_t)gr * 128 + k);
        }
    }
    __syncthreads();

    int colg = (tid & 31) * 4;
    int rowg = (tid >> 5) * 8;
    float as4[4], ad4[4];
#pragma unroll
    for (int j = 0; j < 4; ++j) {
        as4[j] = attf[colg + j];
        ad4[j] = attf[128 + colg + j];
    }
    float acc[8][4];
#pragma unroll
    for (int r = 0; r < 8; ++r)
#pragma unroll
        for (int j = 0; j < 4; ++j) acc[r][j] = 0.f;

#pragma unroll 2
    for (int k0 = 0; k0 < 128; k0 += 4) {
        float4 w0 = *(const float4*)(Wf + (k0 + 0) * 128 + colg);
        float4 w1 = *(const float4*)(Wf + (k0 + 1) * 128 + colg);
        float4 w2 = *(const float4*)(Wf + (k0 + 2) * 128 + colg);
        float4 w3 = *(const float4*)(Wf + (k0 + 3) * 128 + colg);
#pragma unroll
        for (int r = 0; r < 8; ++r) {
            float4 x4 = *(const float4*)(&xs[(rowg + r) * 128 + k0]);
            acc[r][0] += x4.x * w0.x + x4.y * w1.x + x4.z * w2.x + x4.w * w3.x;
            acc[r][1] += x4.x * w0.y + x4.y * w1.y + x4.z * w2.y + x4.w * w3.y;
            acc[r][2] += x4.x * w0.z + x4.y * w1.z + x4.z * w2.z + x4.w * w3.z;
            acc[r][3] += x4.x * w0.w + x4.y * w1.w + x4.z * w2.w + x4.w * w3.w;
        }
    }

    int hd = colg >> 5;
#pragma unroll
    for (int r = 0; r < 8; ++r) {
        int gr = r0 + rowg + r;
        float s1 = acc[r][0] * as4[0] + acc[r][1] * as4[1] + acc[r][2] * as4[2] + acc[r][3] * as4[3];
        float s2 = acc[r][0] * ad4[0] + acc[r][1] * ad4[1] + acc[r][2] * ad4[2] + acc[r][3] * ad4[3];
#pragma unroll
        for (int m = 1; m < 8; m <<= 1) {
            s1 += __shfl_xor(s1, m);
            s2 += __shfl_xor(s2, m);
        }
        if ((tid & 7) == 0 && gr < N) {
            asf[(size_t)gr * 4 + hd] = s1;
            adf[(size_t)gr * 4 + hd] = s2;
        }
        if (gr < N) {
            ushort4 hv;
            hv.x = f2b(acc[r][0]); hv.y = f2b(acc[r][1]);
            hv.z = f2b(acc[r][2]); hv.w = f2b(acc[r][3]);
            *(ushort4*)(&hbf[(size_t)gr * 128 + colg]) = hv;
        }
    }
}

// --- 2. slotted CSR: init (self-loop at slot 0) + single scatter pass -------
__global__ void k_init(int* cnt, int* esrc, int N) {
    int n = blockIdx.x * 256 + threadIdx.x;
    if (n < N) { cnt[n] = 1; esrc[(size_t)n * SLOT] = n; }
}

__global__ void k_scatter(const int* __restrict__ idx32, const long long* __restrict__ idx64,
                          const int* __restrict__ flags, int* cnt, int* esrc, int E) {
    int is64 = flags[0];
    int base = (blockIdx.x * 256 + threadIdx.x) * 4;
    if (base + 3 < E) {
        int s0, s1, s2, s3, d0, d1, d2, d3;
        if (is64) {
            s0 = (int)idx64[base];     s1 = (int)idx64[base + 1];
            s2 = (int)idx64[base + 2]; s3 = (int)idx64[base + 3];
            d0 = (int)idx64[(long long)E + base];     d1 = (int)idx64[(long long)E + base + 1];
            d2 = (int)idx64[(long long)E + base + 2]; d3 = (int)idx64[(long long)E + base + 3];
        } else {
            s0 = idx32[base];     s1 = idx32[base + 1];
            s2 = idx32[base + 2]; s3 = idx32[base + 3];
            d0 = idx32[E + base];     d1 = idx32[E + base + 1];
            d2 = idx32[E + base + 2]; d3 = idx32[E + base + 3];
        }
        int p0 = atomicAdd(&cnt[d0], 1);   // 4 independent atomics in flight
        int p1 = atomicAdd(&cnt[d1], 1);
        int p2 = atomicAdd(&cnt[d2], 1);
        int p3 = atomicAdd(&cnt[d3], 1);
        if (p0 < SLOT) esrc[(size_t)d0 * SLOT + p0] = s0;
        if (p1 < SLOT) esrc[(size_t)d1 * SLOT + p1] = s1;
        if (p2 < SLOT) esrc[(size_t)d2 * SLOT + p2] = s2;
        if (p3 < SLOT) esrc[(size_t)d3 * SLOT + p3] = s3;
    } else {
        for (int e = base; e < E; ++e) {
            int s = edge_at(idx32, idx64, is64, e);
            int d = edge_at(idx32, idx64, is64, (long long)E + e);
            int p = atomicAdd(&cnt[d], 1);
            if (p < SLOT) esrc[(size_t)d * SLOT + p] = s;
        }
    }
}

// --- 3. aggregate: one wave per node (4 nodes / 256-thr block). -------------
//  lane covers channels 2*lane, 2*lane+1 (head = lane>>4). Phase1: edge=lane.
__global__ __launch_bounds__(256) void k_aggregate(
    const unsigned short* __restrict__ hbf,
    const float* __restrict__ asf, const float* __restrict__ adf,
    const int* __restrict__ cnt, const int* __restrict__ esrc,
    const int* __restrict__ idx32, const long long* __restrict__ idx64,
    const float* __restrict__ biasf, const int* __restrict__ flags,
    void* __restrict__ outv, int N, int E) {
    __shared__ float p_sh_all[4][SLOT * 4];
    __shared__ int   s_sh_all[4][SLOT];
    int wid = threadIdx.x >> 6;
    int lane = threadIdx.x & 63;
    int n = blockIdx.x * 4 + wid;
    if (n >= N) n = N - 1;                     // tail waves redo a node (benign)
    float* p_sh = p_sh_all[wid];
    int*   s_sh = s_sh_all[wid];
    int head = lane >> 4;

    int deg = cnt[n];
    float4 adv = *(const float4*)(adf + (size_t)n * 4);
    bool fb = (deg > SLOT);

    float p0 = 0.f, p1 = 0.f, p2 = 0.f, p3 = 0.f;
    if (!fb && lane < deg) {                   // phase 1: one edge per lane
        int s = esrc[(size_t)n * SLOT + lane];
        float4 av = *(const float4*)(asf + (size_t)s * 4);
        float e0 = av.x + adv.x; e0 = fmaxf(e0, 0.2f * e0); p0 = __expf(e0);
        float e1 = av.y + adv.y; e1 = fmaxf(e1, 0.2f * e1); p1 = __expf(e1);
        float e2 = av.z + adv.z; e2 = fmaxf(e2, 0.2f * e2); p2 = __expf(e2);
        float e3 = av.w + adv.w; e3 = fmaxf(e3, 0.2f * e3); p3 = __expf(e3);
        s_sh[lane] = s;
        p_sh[lane * 4 + 0] = p0; p_sh[lane * 4 + 1] = p1;
        p_sh[lane * 4 + 2] = p2; p_sh[lane * 4 + 3] = p3;
    }
    __syncthreads();                           // LDS visibility (uniform path)

    float b0 = biasf[2 * lane], b1 = biasf[2 * lane + 1];
    float a0 = 0.f, a1 = 0.f, invh;

    if (!fb) {
        float ps0 = p0, ps1 = p1, ps2 = p2, ps3 = p3;
#pragma unroll
        for (int m = 1; m < 64; m <<= 1) {     // 64-lane butterfly
            ps0 += __shfl_xor(ps0, m);
            ps1 += __shfl_xor(ps1, m);
            ps2 += __shfl_xor(ps2, m);
            ps3 += __shfl_xor(ps3, m);
        }
        float den = head == 0 ? ps0 : head == 1 ? ps1 : head == 2 ? ps2 : ps3;
        invh = 1.0f / (den + 1e-16f);

        int i = 0;
        for (; i + 3 < deg; i += 4) {          // 4 row-gathers in flight
            int s0 = s_sh[i], s1 = s_sh[i + 1], s2 = s_sh[i + 2], s3 = s_sh[i + 3];
            float q0 = p_sh[i * 4 + head],       q1 = p_sh[(i + 1) * 4 + head];
            float q2 = p_sh[(i + 2) * 4 + head], q3 = p_sh[(i + 3) * 4 + head];
            unsigned int v0 = *(const unsigned int*)(hbf + (size_t)s0 * 128 + 2 * lane);
            unsigned int v1 = *(const unsigned int*)(hbf + (size_t)s1 * 128 + 2 * lane);
            unsigned int v2 = *(const unsigned int*)(hbf + (size_t)s2 * 128 + 2 * lane);
            unsigned int v3 = *(const unsigned int*)(hbf + (size_t)s3 * 128 + 2 * lane);
            a0 += q0 * b2f((unsigned short)v0) + q1 * b2f((unsigned short)v1)
                + q2 * b2f((unsigned short)v2) + q3 * b2f((unsigned short)v3);
            a1 += q0 * b2f((unsigned short)(v0 >> 16)) + q1 * b2f((unsigned short)(v1 >> 16))
                + q2 * b2f((unsigned short)(v2 >> 16)) + q3 * b2f((unsigned short)(v3 >> 16));
        }
        for (; i < deg; ++i) {
            int s0 = s_sh[i];
            float q0 = p_sh[i * 4 + head];
            unsigned int v0 = *(const unsigned int*)(hbf + (size_t)s0 * 128 + 2 * lane);
            a0 += q0 * b2f((unsigned short)v0);
            a1 += q0 * b2f((unsigned short)(v0 >> 16));
        }
    } else {
        // parachute: degree > SLOT (statistically never). Full edge scan,
        // per-lane redundant denominator for its own head.
        int is64 = flags[0];
        float adh = head == 0 ? adv.x : head == 1 ? adv.y : head == 2 ? adv.z : adv.w;
        float den = 0.f;
        {   // self-loop
            float ev = asf[(size_t)n * 4 + head] + adh; ev = fmaxf(ev, 0.2f * ev);
            float p = __expf(ev);
            unsigned int v = *(const unsigned int*)(hbf + (size_t)n * 128 + 2 * lane);
            den += p;
            a0 += p * b2f((unsigned short)v);
            a1 += p * b2f((unsigned short)(v >> 16));
        }
        for (int e = 0; e < E; ++e) {
            int d = edge_at(idx32, idx64, is64, (long long)E + e);
            if (d == n) {
                int s = edge_at(idx32, idx64, is64, e);
                float ev = asf[(size_t)s * 4 + head] + adh; ev = fmaxf(ev, 0.2f * ev);
                float p = __expf(ev);
                unsigned int v = *(const unsigned int*)(hbf + (size_t)s * 128 + 2 * lane);
                den += p;
                a0 += p * b2f((unsigned short)v);
                a1 += p * b2f((unsigned short)(v >> 16));
            }
        }
        invh = 1.0f / (den + 1e-16f);
    }

    a0 = a0 * invh + b0;
    a1 = a1 * invh + b1;
    if (flags[1]) {
        unsigned int pk = (unsigned int)f2b(a0) | ((unsigned int)f2b(a1) << 16);
        ((unsigned int*)outv)[(size_t)n * 64 + lane] = pk;
    } else {
        float2 f2; f2.x = a0; f2.y = a1;
        *(float2*)((float*)outv + (size_t)n * 128 + 2 * lane) = f2;
    }
}

// ---------------------------------------------------------------------------
extern "C" void kernel_launch(void* const* d_in, const int* in_sizes, int n_in,
                              void* d_out, int out_size, void* d_ws, size_t ws_size,
                              hipStream_t stream) {
    const void*      xv    = d_in[0];
    const int*       idx32 = (const int*)d_in[1];
    const long long* idx64 = (const long long*)d_in[1];

    int N = in_sizes[0] / 128;
    int E = in_sizes[1] / 2;

    char* ws = (char*)d_ws;
    size_t o = 0;
    auto alloc = [&](size_t bytes) {
        size_t r = o; o += (bytes + 255) & ~(size_t)255; return r;
    };
    unsigned short* hbf = (unsigned short*)(ws + alloc((size_t)N * 128 * 2));
    float* Wf    = (float*)(ws + alloc(16384 * 4));
    float* attf  = (float*)(ws + alloc(256 * 4));
    float* biasf = (float*)(ws + alloc(128 * 4));
    float* asf   = (float*)(ws + alloc((size_t)N * 4 * 4));
    float* adf   = (float*)(ws + alloc((size_t)N * 4 * 4));
    int* cnt     = (int*)(ws + alloc((size_t)N * 4));
    int* flags   = (int*)(ws + alloc(256));
    int* esrc    = (int*)(ws + alloc((size_t)N * SLOT * 4));

    k_detect<<<1, 256, 0, stream>>>(idx32, (const unsigned int*)xv, flags);
    k_prep<<<16, 256, 0, stream>>>(d_in[2], d_in[3], d_in[4], d_in[5], flags, Wf, attf, biasf);
    k_gemm<<<(N + 63) / 64, 256, 0, stream>>>(xv, Wf, attf, flags, hbf, asf, adf, N);
    k_init<<<(N + 255) / 256, 256, 0, stream>>>(cnt, esrc, N);
    k_scatter<<<(E / 4 + 255) / 256, 256, 0, stream>>>(idx32, idx64, flags, cnt, esrc, E);
    k_aggregate<<<(N + 3) / 4, 256, 0, stream>>>(hbf, asf, adf, cnt, esrc, idx32, idx64,
                                                 biasf, flags, d_out, N, E);
}

// Round 8
// 301.671 us; speedup vs baseline: 1.7347x; 1.2561x over previous
//
#include <hip/hip_runtime.h>
#include <stdint.h>

// ---------------------------------------------------------------------------
// GAT layer, dtype-adaptive (probed: fp32 inputs, int32 edge_index, bf16 out).
//   fused:  h = x@W (fp32 GEMM, attn dots in epilogue, h->bf16)  [even blocks]
//           slotted-CSR scatter, 64B-padded counters             [odd  blocks]
//   aggregate: one wave/node, self-loop at lane 0, butterfly softmax denom,
//              dword gathers (2 ch/lane), 4 in flight.
// ---------------------------------------------------------------------------

#define SLOT 64
#define CNTS 16   // counter stride in ints = one 64B line per node

__device__ __forceinline__ float b2f(unsigned short u) {
    union { unsigned int i; float f; } v; v.i = ((unsigned int)u) << 16; return v.f;
}
__device__ __forceinline__ unsigned short f2b(float f) {
    union { float f; unsigned int i; } v; v.f = f;
    unsigned int i = v.i;
    unsigned int r = (i + 0x7FFFu + ((i >> 16) & 1u)) >> 16;  // RNE
    return (unsigned short)r;
}

// --- 0. dtype probes --------------------------------------------------------
__global__ void k_detect(const int* __restrict__ eidx, const unsigned int* __restrict__ xw,
                         int* flags) {
    __shared__ int nz, bf;
    if (threadIdx.x == 0) { nz = 0; bf = 0; }
    __syncthreads();
    int bad = 0;
    for (int i = threadIdx.x; i < 1024; i += 256)
        if (eidx[2 * i + 1] != 0) bad = 1;
    if (bad) atomicOr(&nz, 1);
    int hits = 0;
    for (int i = threadIdx.x; i < 4096; i += 256) {
        unsigned int e = (xw[i] >> 7) & 0xFFu;
        if (e >= 0x60u && e < 0xA0u) ++hits;
    }
    atomicAdd(&bf, hits);
    __syncthreads();
    if (threadIdx.x == 0) {
        flags[0] = (nz == 0) ? 1 : 0;   // 1 => int64 edge_index
        flags[1] = (bf > 3072) ? 1 : 0; // 1 => bf16 float tensors
    }
}

__device__ __forceinline__ int edge_at(const int* idx32, const long long* idx64,
                                       int is64, long long pos) {
    return is64 ? (int)idx64[pos] : idx32[pos];
}

// --- 0b. W / att / bias -> fp32 in ws ---------------------------------------
__global__ void k_prep(const void* __restrict__ Wv, const void* __restrict__ asv,
                       const void* __restrict__ adv, const void* __restrict__ bv,
                       const int* __restrict__ flags,
                       float* __restrict__ Wf, float* __restrict__ attf /*256*/,
                       float* __restrict__ biasf /*128*/) {
    int isbf = flags[1];
    int tid = blockIdx.x * 256 + threadIdx.x;
    for (int i = tid; i < 16384; i += gridDim.x * 256)
        Wf[i] = isbf ? b2f(((const unsigned short*)Wv)[i]) : ((const float*)Wv)[i];
    if (blockIdx.x == 0) {
        for (int i = threadIdx.x; i < 128; i += 256) {
            attf[i]       = isbf ? b2f(((const unsigned short*)asv)[i]) : ((const float*)asv)[i];
            attf[128 + i] = isbf ? b2f(((const unsigned short*)adv)[i]) : ((const float*)adv)[i];
            biasf[i]      = isbf ? b2f(((const unsigned short*)bv)[i]) : ((const float*)bv)[i];
        }
    }
}

// --- 1. fused GEMM (even blocks) + scatter (odd blocks) ---------------------
__global__ __launch_bounds__(256) void k_gemm_scatter(
    const void* __restrict__ xv, const float* __restrict__ Wf,
    const float* __restrict__ attf, const int* __restrict__ flags,
    unsigned short* __restrict__ hbf, float* __restrict__ asf,
    float* __restrict__ adf, int N,
    const int* __restrict__ idx32, const long long* __restrict__ idx64,
    int* __restrict__ cnt, int* __restrict__ esrc, int E, int Gg, int Gs) {
    __shared__ float xs[64 * 128];
    int role = blockIdx.x & 1, rb = blockIdx.x >> 1;
    int tid = threadIdx.x;

    if (role == 1) {                           // ---- scatter ----
        if (rb >= Gs) return;
        int is64 = flags[0];
        int base = (rb * 256 + tid) * 4;
        if (base + 3 < E) {
            int s0, s1, s2, s3, d0, d1, d2, d3;
            if (is64) {
                s0 = (int)idx64[base];     s1 = (int)idx64[base + 1];
                s2 = (int)idx64[base + 2]; s3 = (int)idx64[base + 3];
                d0 = (int)idx64[(long long)E + base];     d1 = (int)idx64[(long long)E + base + 1];
                d2 = (int)idx64[(long long)E + base + 2]; d3 = (int)idx64[(long long)E + base + 3];
            } else if ((E & 3) == 0) {
                int4 sv = *(const int4*)(idx32 + base);
                int4 dv = *(const int4*)(idx32 + E + base);
                s0 = sv.x; s1 = sv.y; s2 = sv.z; s3 = sv.w;
                d0 = dv.x; d1 = dv.y; d2 = dv.z; d3 = dv.w;
            } else {
                s0 = idx32[base];     s1 = idx32[base + 1];
                s2 = idx32[base + 2]; s3 = idx32[base + 3];
                d0 = idx32[E + base];     d1 = idx32[E + base + 1];
                d2 = idx32[E + base + 2]; d3 = idx32[E + base + 3];
            }
            int p0 = atomicAdd(&cnt[(size_t)d0 * CNTS], 1);  // 4 independent chains
            int p1 = atomicAdd(&cnt[(size_t)d1 * CNTS], 1);
            int p2 = atomicAdd(&cnt[(size_t)d2 * CNTS], 1);
            int p3 = atomicAdd(&cnt[(size_t)d3 * CNTS], 1);
            if (p0 < SLOT) esrc[(size_t)d0 * SLOT + p0] = s0;
            if (p1 < SLOT) esrc[(size_t)d1 * SLOT + p1] = s1;
            if (p2 < SLOT) esrc[(size_t)d2 * SLOT + p2] = s2;
            if (p3 < SLOT) esrc[(size_t)d3 * SLOT + p3] = s3;
        } else {
            for (int e = base; e < E; ++e) {
                int s = edge_at(idx32, idx64, is64, e);
                int d = edge_at(idx32, idx64, is64, (long long)E + e);
                int p = atomicAdd(&cnt[(size_t)d * CNTS], 1);
                if (p < SLOT) esrc[(size_t)d * SLOT + p] = s;
            }
        }
        return;
    }

    // ---- GEMM ----
    if (rb >= Gg) return;
    int r0 = rb * 64;
    int isbf = flags[1];
    if (isbf) {
        const unsigned short* xb = (const unsigned short*)xv;
#pragma unroll
        for (int it = 0; it < 8; ++it) {
            int e = it * 1024 + tid * 4;
            int r = e >> 7, k = e & 127;
            int gr = r0 + r; if (gr >= N) gr = N - 1;
            ushort4 v = *(const ushort4*)(xb + (size_t)gr * 128 + k);
            float4 f; f.x = b2f(v.x); f.y = b2f(v.y); f.z = b2f(v.z); f.w = b2f(v.w);
            *(float4*)(&xs[r * 128 + k]) = f;
        }
    } else {
        const float* xf = (const float*)xv;
#pragma unroll
        for (int it = 0; it < 8; ++it) {
            int e = it * 1024 + tid * 4;
            int r = e >> 7, k = e & 127;
            int gr = r0 + r; if (gr >= N) gr = N - 1;
            *(float4*)(&xs[r * 128 + k]) = *(const float4*)(xf + (size_t)gr * 128 + k);
        }
    }
    __syncthreads();

    int colg = (tid & 31) * 4;
    int rowg = (tid >> 5) * 8;
    float as4[4], ad4[4];
#pragma unroll
    for (int j = 0; j < 4; ++j) {
        as4[j] = attf[colg + j];
        ad4[j] = attf[128 + colg + j];
    }
    float acc[8][4];
#pragma unroll
    for (int r = 0; r < 8; ++r)
#pragma unroll
        for (int j = 0; j < 4; ++j) acc[r][j] = 0.f;

#pragma unroll 2
    for (int k0 = 0; k0 < 128; k0 += 4) {
        float4 w0 = *(const float4*)(Wf + (k0 + 0) * 128 + colg);
        float4 w1 = *(const float4*)(Wf + (k0 + 1) * 128 + colg);
        float4 w2 = *(const float4*)(Wf + (k0 + 2) * 128 + colg);
        float4 w3 = *(const float4*)(Wf + (k0 + 3) * 128 + colg);
#pragma unroll
        for (int r = 0; r < 8; ++r) {
            float4 x4 = *(const float4*)(&xs[(rowg + r) * 128 + k0]);
            acc[r][0] += x4.x * w0.x + x4.y * w1.x + x4.z * w2.x + x4.w * w3.x;
            acc[r][1] += x4.x * w0.y + x4.y * w1.y + x4.z * w2.y + x4.w * w3.y;
            acc[r][2] += x4.x * w0.z + x4.y * w1.z + x4.z * w2.z + x4.w * w3.z;
            acc[r][3] += x4.x * w0.w + x4.y * w1.w + x4.z * w2.w + x4.w * w3.w;
        }
    }

    int hd = colg >> 5;
#pragma unroll
    for (int r = 0; r < 8; ++r) {
        int gr = r0 + rowg + r;
        float s1 = acc[r][0] * as4[0] + acc[r][1] * as4[1] + acc[r][2] * as4[2] + acc[r][3] * as4[3];
        float s2 = acc[r][0] * ad4[0] + acc[r][1] * ad4[1] + acc[r][2] * ad4[2] + acc[r][3] * ad4[3];
#pragma unroll
        for (int m = 1; m < 8; m <<= 1) {
            s1 += __shfl_xor(s1, m);
            s2 += __shfl_xor(s2, m);
        }
        if ((tid & 7) == 0 && gr < N) {
            asf[(size_t)gr * 4 + hd] = s1;
            adf[(size_t)gr * 4 + hd] = s2;
        }
        if (gr < N) {
            ushort4 hv;
            hv.x = f2b(acc[r][0]); hv.y = f2b(acc[r][1]);
            hv.z = f2b(acc[r][2]); hv.w = f2b(acc[r][3]);
            *(ushort4*)(&hbf[(size_t)gr * 128 + colg]) = hv;
        }
    }
}

// --- 2. aggregate: one wave per node; self-loop = lane 0 --------------------
__global__ __launch_bounds__(256) void k_aggregate(
    const unsigned short* __restrict__ hbf,
    const float* __restrict__ asf, const float* __restrict__ adf,
    const int* __restrict__ cnt, const int* __restrict__ esrc,
    const int* __restrict__ idx32, const long long* __restrict__ idx64,
    const float* __restrict__ biasf, const int* __restrict__ flags,
    void* __restrict__ outv, int N, int E) {
    __shared__ float p_sh_all[4][SLOT * 4];
    __shared__ int   s_sh_all[4][SLOT];
    int wid = threadIdx.x >> 6;
    int lane = threadIdx.x & 63;
    int n = blockIdx.x * 4 + wid;
    if (n >= N) n = N - 1;                     // tail waves redo a node (benign)
    float* p_sh = p_sh_all[wid];
    int*   s_sh = s_sh_all[wid];
    int head = lane >> 4;

    int deg = cnt[(size_t)n * CNTS];           // edges, excl. self-loop
    float4 adv = *(const float4*)(adf + (size_t)n * 4);
    bool fb = (deg > SLOT - 1);                // total deg+1 must fit in 64

    float p0 = 0.f, p1 = 0.f, p2 = 0.f, p3 = 0.f;
    if (!fb && lane <= deg) {                  // phase 1: one item per lane
        int s = (lane == 0) ? n : esrc[(size_t)n * SLOT + lane - 1];
        float4 av = *(const float4*)(asf + (size_t)s * 4);
        float e0 = av.x + adv.x; e0 = fmaxf(e0, 0.2f * e0); p0 = __expf(e0);
        float e1 = av.y + adv.y; e1 = fmaxf(e1, 0.2f * e1); p1 = __expf(e1);
        float e2 = av.z + adv.z; e2 = fmaxf(e2, 0.2f * e2); p2 = __expf(e2);
        float e3 = av.w + adv.w; e3 = fmaxf(e3, 0.2f * e3); p3 = __expf(e3);
        s_sh[lane] = s;
        p_sh[lane * 4 + 0] = p0; p_sh[lane * 4 + 1] = p1;
        p_sh[lane * 4 + 2] = p2; p_sh[lane * 4 + 3] = p3;
    }
    __syncthreads();

    float b0 = biasf[2 * lane], b1 = biasf[2 * lane + 1];
    float a0 = 0.f, a1 = 0.f, invh;

    if (!fb) {
        float ps0 = p0, ps1 = p1, ps2 = p2, ps3 = p3;
#pragma unroll
        for (int m = 1; m < 64; m <<= 1) {     // 64-lane butterfly
            ps0 += __shfl_xor(ps0, m);
            ps1 += __shfl_xor(ps1, m);
            ps2 += __shfl_xor(ps2, m);
            ps3 += __shfl_xor(ps3, m);
        }
        float den = head == 0 ? ps0 : head == 1 ? ps1 : head == 2 ? ps2 : ps3;
        invh = 1.0f / (den + 1e-16f);

        int tot = deg + 1;
        int i = 0;
        for (; i + 3 < tot; i += 4) {          // 4 row-gathers in flight
            int s0 = s_sh[i], s1 = s_sh[i + 1], s2 = s_sh[i + 2], s3 = s_sh[i + 3];
            float q0 = p_sh[i * 4 + head],       q1 = p_sh[(i + 1) * 4 + head];
            float q2 = p_sh[(i + 2) * 4 + head], q3 = p_sh[(i + 3) * 4 + head];
            unsigned int v0 = *(const unsigned int*)(hbf + (size_t)s0 * 128 + 2 * lane);
            unsigned int v1 = *(const unsigned int*)(hbf + (size_t)s1 * 128 + 2 * lane);
            unsigned int v2 = *(const unsigned int*)(hbf + (size_t)s2 * 128 + 2 * lane);
            unsigned int v3 = *(const unsigned int*)(hbf + (size_t)s3 * 128 + 2 * lane);
            a0 += q0 * b2f((unsigned short)v0) + q1 * b2f((unsigned short)v1)
                + q2 * b2f((unsigned short)v2) + q3 * b2f((unsigned short)v3);
            a1 += q0 * b2f((unsigned short)(v0 >> 16)) + q1 * b2f((unsigned short)(v1 >> 16))
                + q2 * b2f((unsigned short)(v2 >> 16)) + q3 * b2f((unsigned short)(v3 >> 16));
        }
        for (; i < tot; ++i) {
            int s0 = s_sh[i];
            float q0 = p_sh[i * 4 + head];
            unsigned int v0 = *(const unsigned int*)(hbf + (size_t)s0 * 128 + 2 * lane);
            a0 += q0 * b2f((unsigned short)v0);
            a1 += q0 * b2f((unsigned short)(v0 >> 16));
        }
    } else {
        // parachute: degree >= SLOT (statistically never). Full edge rescan.
        int is64 = flags[0];
        float adh = head == 0 ? adv.x : head == 1 ? adv.y : head == 2 ? adv.z : adv.w;
        float den = 0.f;
        {   // self-loop
            float ev = asf[(size_t)n * 4 + head] + adh; ev = fmaxf(ev, 0.2f * ev);
            float p = __expf(ev);
            unsigned int v = *(const unsigned int*)(hbf + (size_t)n * 128 + 2 * lane);
            den += p;
            a0 += p * b2f((unsigned short)v);
            a1 += p * b2f((unsigned short)(v >> 16));
        }
        for (int e = 0; e < E; ++e) {
            int d = edge_at(idx32, idx64, is64, (long long)E + e);
            if (d == n) {
                int s = edge_at(idx32, idx64, is64, e);
                float ev = asf[(size_t)s * 4 + head] + adh; ev = fmaxf(ev, 0.2f * ev);
                float p = __expf(ev);
                unsigned int v = *(const unsigned int*)(hbf + (size_t)s * 128 + 2 * lane);
                den += p;
                a0 += p * b2f((unsigned short)v);
                a1 += p * b2f((unsigned short)(v >> 16));
            }
        }
        invh = 1.0f / (den + 1e-16f);
    }

    a0 = a0 * invh + b0;
    a1 = a1 * invh + b1;
    if (flags[1]) {
        unsigned int pk = (unsigned int)f2b(a0) | ((unsigned int)f2b(a1) << 16);
        ((unsigned int*)outv)[(size_t)n * 64 + lane] = pk;
    } else {
        float2 f2; f2.x = a0; f2.y = a1;
        *(float2*)((float*)outv + (size_t)n * 128 + 2 * lane) = f2;
    }
}

// ---------------------------------------------------------------------------
extern "C" void kernel_launch(void* const* d_in, const int* in_sizes, int n_in,
                              void* d_out, int out_size, void* d_ws, size_t ws_size,
                              hipStream_t stream) {
    const void*      xv    = d_in[0];
    const int*       idx32 = (const int*)d_in[1];
    const long long* idx64 = (const long long*)d_in[1];

    int N = in_sizes[0] / 128;
    int E = in_sizes[1] / 2;

    char* ws = (char*)d_ws;
    size_t o = 0;
    auto alloc = [&](size_t bytes) {
        size_t r = o; o += (bytes + 255) & ~(size_t)255; return r;
    };
    unsigned short* hbf = (unsigned short*)(ws + alloc((size_t)N * 128 * 2));
    float* Wf    = (float*)(ws + alloc(16384 * 4));
    float* attf  = (float*)(ws + alloc(256 * 4));
    float* biasf = (float*)(ws + alloc(128 * 4));
    float* asf   = (float*)(ws + alloc((size_t)N * 4 * 4));
    float* adf   = (float*)(ws + alloc((size_t)N * 4 * 4));
    int* cnt     = (int*)(ws + alloc((size_t)N * CNTS * 4));
    int* flags   = (int*)(ws + alloc(256));
    int* esrc    = (int*)(ws + alloc((size_t)N * SLOT * 4));

    int Gg = (N + 63) / 64;
    int Gs = (E / 4 + 255) / 256;
    int G2 = (Gg > Gs ? Gg : Gs);

    k_detect<<<1, 256, 0, stream>>>(idx32, (const unsigned int*)xv, flags);
    k_prep<<<16, 256, 0, stream>>>(d_in[2], d_in[3], d_in[4], d_in[5], flags, Wf, attf, biasf);
    hipMemsetAsync(cnt, 0, (size_t)N * CNTS * 4, stream);
    k_gemm_scatter<<<2 * G2, 256, 0, stream>>>(xv, Wf, attf, flags, hbf, asf, adf, N,
                                               idx32, idx64, cnt, esrc, E, Gg, Gs);
    k_aggregate<<<(N + 3) / 4, 256, 0, stream>>>(hbf, asf, adf, cnt, esrc, idx32, idx64,
                                                 biasf, flags, d_out, N, E);
}